// Round 12
// baseline (214.203 us; speedup 1.0000x reference)
//
#include <hip/hip_runtime.h>
#include <math.h>

// CriterionLSCos: MSE between 8-neighbor cosine-similarity maps of two
// [16,19,256,256] fp32 tensors.
//
// (Unchanged resubmit — R11 bench was a broker timeout.)
//
// R10 post-mortem: shuffle-stencil structure is sound (88 VGPR, no spill,
// no LDS, 97us) but HBM-bound on 3x vertical over-read (~470MB): with
// gridDim.x=1 the linear block id = by + 64*z round-robins across XCDs,
// so vertically-adjacent row-blocks sit on DIFFERENT per-XCD L2s and each
// re-fetches shared rows from HBM.
//
// R11 = R10 + bijective XCD chunk swizzle (T1): row_group = bit-swap of
// blockIdx.y (low3 <-> high3). XCD k (= by%8) then owns a contiguous
// 32-row span for all batches; adjacent groups dispatch consecutively on
// the same XCD -> row re-reads hit that XCD's 4MB L2, HBM ~= unique bytes.
//
// Structure (R10, passed):
//   - NO LDS, NO barriers: one wave == one image row (64 lanes x 4 px).
//     x-neighbors + neighbor norms via __shfl; vertical reuse via L2.
//   - 6 aligned float4 loads per channel per wave, 1-deep prefetch.
//   - per-wave shuffle reduction -> one double atomicAdd per wave.

constexpr int BATCH = 16, CH = 19, H = 256, W = 256;
constexpr int HW = H * W;
constexpr int CS4 = HW / 4;  // channel stride in float4

__global__ __launch_bounds__(256)   // no min-waves arg (R7/R8 lesson)
void cosmap_mse_kernel(const float* __restrict__ preds,
                       const float* __restrict__ soft,
                       double* __restrict__ acc_out) {
  const int lane = threadIdx.x & 63;
  const int wid = threadIdx.x >> 6;
  // XCD chunk swizzle: swap low-3/high-3 bits of by (bijective on [0,64)).
  // XCD = linear_id % 8 = by % 8 (gridDim.x==1, 64*z % 8 == 0), so XCD k
  // processes row groups 8k..8k+7 = a contiguous 32-row span.
  const int g = ((blockIdx.y & 7) << 3) | (blockIdx.y >> 3);
  const int y = 1 + (g << 2) + wid;            // this wave's center row
  if (y > H - 2) return;                       // no barriers -> safe
  const size_t base = (size_t)blockIdx.z * (CH * HW);

  // row pointers (float4 granularity), lane offset folded in
  const float4* PU = (const float4*)(preds + base + (size_t)(y - 1) * W) + lane;
  const float4* PM = PU + (W / 4);
  const float4* PL = PM + (W / 4);
  const float4* SU = (const float4*)(soft + base + (size_t)(y - 1) * W) + lane;
  const float4* SM = SU + (W / 4);
  const float4* SL = SM + (W / 4);

  float dp[8][4], dq[8][4];   // 8 directions x 4 centers, preds/soft
  float np[3][4], nq[3][4];   // self-norms rows {u,m,l} x 4 px
#pragma unroll
  for (int d = 0; d < 8; ++d)
#pragma unroll
    for (int e = 0; e < 4; ++e) { dp[d][e] = 0.f; dq[d][e] = 0.f; }
#pragma unroll
  for (int r = 0; r < 3; ++r)
#pragma unroll
    for (int e = 0; e < 4; ++e) { np[r][e] = 0.f; nq[r][e] = 0.f; }

  // 1-deep prefetch (no barriers -> loads overlap previous channel's FMAs)
  float4 au = PU[0], am = PM[0], al = PL[0];
  float4 bu = SU[0], bm = SM[0], bl = SL[0];

  for (int c = 0; c < CH; ++c) {
    const float4 cu = au, cm = am, cl = al, eu = bu, em = bm, el = bl;
    if (c + 1 < CH) {
      const int o = (c + 1) * CS4;
      au = PU[o]; am = PM[o]; al = PL[o];
      bu = SU[o]; bm = SM[o]; bl = SL[o];
    }
    // x-window [4*lane-1 .. 4*lane+4]; wrap lanes feed only masked centers
    const float wu[6] = {__shfl_up(cu.w, 1), cu.x, cu.y, cu.z, cu.w, __shfl_down(cu.x, 1)};
    const float wm[6] = {__shfl_up(cm.w, 1), cm.x, cm.y, cm.z, cm.w, __shfl_down(cm.x, 1)};
    const float wl[6] = {__shfl_up(cl.w, 1), cl.x, cl.y, cl.z, cl.w, __shfl_down(cl.x, 1)};
    const float vu[6] = {__shfl_up(eu.w, 1), eu.x, eu.y, eu.z, eu.w, __shfl_down(eu.x, 1)};
    const float vm[6] = {__shfl_up(em.w, 1), em.x, em.y, em.z, em.w, __shfl_down(em.x, 1)};
    const float vl[6] = {__shfl_up(el.w, 1), el.x, el.y, el.z, el.w, __shfl_down(el.x, 1)};
#pragma unroll
    for (int e = 0; e < 4; ++e) {
      np[0][e] = fmaf(wu[e + 1], wu[e + 1], np[0][e]);
      np[1][e] = fmaf(wm[e + 1], wm[e + 1], np[1][e]);
      np[2][e] = fmaf(wl[e + 1], wl[e + 1], np[2][e]);
      nq[0][e] = fmaf(vu[e + 1], vu[e + 1], nq[0][e]);
      nq[1][e] = fmaf(vm[e + 1], vm[e + 1], nq[1][e]);
      nq[2][e] = fmaf(vl[e + 1], vl[e + 1], nq[2][e]);
      const float cp = wm[e + 1], cs = vm[e + 1];
      dp[0][e] = fmaf(cp, wu[e],     dp[0][e]); dq[0][e] = fmaf(cs, vu[e],     dq[0][e]); // NW
      dp[1][e] = fmaf(cp, wu[e + 1], dp[1][e]); dq[1][e] = fmaf(cs, vu[e + 1], dq[1][e]); // N
      dp[2][e] = fmaf(cp, wu[e + 2], dp[2][e]); dq[2][e] = fmaf(cs, vu[e + 2], dq[2][e]); // NE
      dp[3][e] = fmaf(cp, wm[e],     dp[3][e]); dq[3][e] = fmaf(cs, vm[e],     dq[3][e]); // W
      dp[4][e] = fmaf(cp, wm[e + 2], dp[4][e]); dq[4][e] = fmaf(cs, vm[e + 2], dq[4][e]); // E
      dp[5][e] = fmaf(cp, wl[e],     dp[5][e]); dq[5][e] = fmaf(cs, vl[e],     dq[5][e]); // SW
      dp[6][e] = fmaf(cp, wl[e + 1], dp[6][e]); dq[6][e] = fmaf(cs, vl[e + 1], dq[6][e]); // S
      dp[7][e] = fmaf(cp, wl[e + 2], dp[7][e]); dq[7][e] = fmaf(cs, vl[e + 2], dq[7][e]); // SE
    }
  }

  // inverse norms (one per pixel), then neighbor-norm windows via shfl
  float rp[3][4], rq[3][4];
#pragma unroll
  for (int r = 0; r < 3; ++r)
#pragma unroll
    for (int e = 0; e < 4; ++e) {
      rp[r][e] = 1.0f / sqrtf(np[r][e]);
      rq[r][e] = 1.0f / sqrtf(nq[r][e]);
    }

  const float xu[6] = {__shfl_up(rp[0][3], 1), rp[0][0], rp[0][1], rp[0][2], rp[0][3], __shfl_down(rp[0][0], 1)};
  const float xm[6] = {__shfl_up(rp[1][3], 1), rp[1][0], rp[1][1], rp[1][2], rp[1][3], __shfl_down(rp[1][0], 1)};
  const float xl[6] = {__shfl_up(rp[2][3], 1), rp[2][0], rp[2][1], rp[2][2], rp[2][3], __shfl_down(rp[2][0], 1)};
  const float zu[6] = {__shfl_up(rq[0][3], 1), rq[0][0], rq[0][1], rq[0][2], rq[0][3], __shfl_down(rq[0][0], 1)};
  const float zm[6] = {__shfl_up(rq[1][3], 1), rq[1][0], rq[1][1], rq[1][2], rq[1][3], __shfl_down(rq[1][0], 1)};
  const float zl[6] = {__shfl_up(rq[2][3], 1), rq[2][0], rq[2][1], rq[2][2], rq[2][3], __shfl_down(rq[2][0], 1)};

  float local = 0.f;
#pragma unroll
  for (int e = 0; e < 4; ++e) {
    const int x = (lane << 2) + e;
    if (x >= 1 && x <= W - 2) {
      const float rcp = rp[1][e], rcq = rq[1][e];
      float mp, ms, t;
      mp = dp[0][e] * rcp * xu[e];     ms = dq[0][e] * rcq * zu[e];     t = mp - ms; local = fmaf(t, t, local);
      mp = dp[1][e] * rcp * xu[e + 1]; ms = dq[1][e] * rcq * zu[e + 1]; t = mp - ms; local = fmaf(t, t, local);
      mp = dp[2][e] * rcp * xu[e + 2]; ms = dq[2][e] * rcq * zu[e + 2]; t = mp - ms; local = fmaf(t, t, local);
      mp = dp[3][e] * rcp * xm[e];     ms = dq[3][e] * rcq * zm[e];     t = mp - ms; local = fmaf(t, t, local);
      mp = dp[4][e] * rcp * xm[e + 2]; ms = dq[4][e] * rcq * zm[e + 2]; t = mp - ms; local = fmaf(t, t, local);
      mp = dp[5][e] * rcp * xl[e];     ms = dq[5][e] * rcq * zl[e];     t = mp - ms; local = fmaf(t, t, local);
      mp = dp[6][e] * rcp * xl[e + 1]; ms = dq[6][e] * rcq * zl[e + 1]; t = mp - ms; local = fmaf(t, t, local);
      mp = dp[7][e] * rcp * xl[e + 2]; ms = dq[7][e] * rcq * zl[e + 2]; t = mp - ms; local = fmaf(t, t, local);
    }
  }

  // per-wave reduction, one atomic per wave (no LDS, no barrier)
#pragma unroll
  for (int o = 32; o > 0; o >>= 1) local += __shfl_down(local, o, 64);
  if (lane == 0) atomicAdd(acc_out, (double)local);
}

__global__ void finalize_kernel(const double* __restrict__ acc,
                                float* __restrict__ out) {
  constexpr double cnt = (double)BATCH * 8.0 * (H - 2) * (W - 2);
  out[0] = (float)(acc[0] / cnt);
}

extern "C" void kernel_launch(void* const* d_in, const int* in_sizes, int n_in,
                              void* d_out, int out_size, void* d_ws, size_t ws_size,
                              hipStream_t stream) {
  const float* preds = (const float*)d_in[0];
  const float* soft = (const float*)d_in[1];
  double* acc = (double*)d_ws;

  hipMemsetAsync(d_ws, 0, sizeof(double), stream);  // ws is 0xAA-poisoned

  // 4 rows per block (4 waves), rows 1..254 -> grid.y = 64
  dim3 block(256);
  dim3 grid(1, (H - 2 + 3) / 4, BATCH);
  cosmap_mse_kernel<<<grid, block, 0, stream>>>(preds, soft, acc);
  finalize_kernel<<<1, 1, 0, stream>>>(acc, (float*)d_out);
}